// Round 7
// baseline (472.927 us; speedup 1.0000x reference)
//
#include <hip/hip_runtime.h>

#define T_SEQ 4096
#define D_EMB 768
#define N_HEAD 12
#define D_HEAD 64
#define D_MLP 3072
#define NTOK 8192   // B*T
#define QSCALE 0.18033688011112043f  // log2(e)/8, folded into Q at qkv epilogue

typedef __bf16 v8bf __attribute__((ext_vector_type(8)));
typedef float v4f __attribute__((ext_vector_type(4)));
typedef short v4s __attribute__((ext_vector_type(4)));
typedef unsigned v2u __attribute__((ext_vector_type(2)));

template <int N> struct IC { static constexpr int value = N; };

__device__ __forceinline__ unsigned short f2bf(float f) {
    unsigned int u = __float_as_uint(f);
    unsigned int r = (u + 0x7fffu + ((u >> 16) & 1u)) >> 16;
    return (unsigned short)r;
}

__device__ __forceinline__ void g2lds16(const void* g, void* l) {
    __builtin_amdgcn_global_load_lds(
        (const __attribute__((address_space(1))) void*)g,
        (__attribute__((address_space(3))) void*)l, 16, 0, 0);
}

__device__ __forceinline__ float fastrcp(float x) {
#if __has_builtin(__builtin_amdgcn_rcpf)
    return __builtin_amdgcn_rcpf(x);
#else
    return 1.f / x;
#endif
}

// row-swap primitives (gfx950): 32-swap gathers half-pairs, 16-swap gathers
// even/odd 16-rows. Composed they turn the S^T C/D layout into exact K32
// A-fragments -- zero LDS traffic, full-rate VALU.
__device__ __forceinline__ void pl32swap(unsigned& a, unsigned& b) {
#if __has_builtin(__builtin_amdgcn_permlane32_swap)
    v2u r = __builtin_amdgcn_permlane32_swap(a, b, false, false);
    a = r[0]; b = r[1];
#else
    asm volatile("v_permlane32_swap_b32 %0, %1" : "+v"(a), "+v"(b));
#endif
}
__device__ __forceinline__ void pl16swap(unsigned& a, unsigned& b) {
#if __has_builtin(__builtin_amdgcn_permlane16_swap)
    v2u r = __builtin_amdgcn_permlane16_swap(a, b, false, false);
    a = r[0]; b = r[1];
#else
    asm volatile("v_permlane16_swap_b32 %0, %1" : "+v"(a), "+v"(b));
#endif
}

// chunk swizzle for 32-short (4x16B) LDS rows: 16-periodic, makes frag reads
// <=2-way bank-aliased (free) instead of 8-way (2.9x, m136)
__device__ __forceinline__ int sg(int r) { return (r ^ (r >> 2)) & 3; }

// ---------------- weight cast + transpose: fp32 [K][N] -> bf16 [N][K] --------
__global__ void tcast_kernel(const float* __restrict__ in, unsigned short* __restrict__ out,
                             int K, int N) {
    __shared__ float tile[32][33];
    int k0 = blockIdx.y * 32, n0 = blockIdx.x * 32;
    int tx = threadIdx.x, ty = threadIdx.y;
    for (int i = ty; i < 32; i += 8)
        tile[i][tx] = in[(size_t)(k0 + i) * N + n0 + tx];
    __syncthreads();
    for (int i = ty; i < 32; i += 8)
        out[(size_t)(n0 + i) * K + k0 + tx] = f2bf(tile[tx][i]);
}

// ------- V transpose, TILED: [bh][t][64] -> [bh][kt][64d][64k] (8KB tiles) ---
__global__ void vtrans_kernel(const unsigned short* __restrict__ in,
                              unsigned short* __restrict__ out) {
    __shared__ unsigned short tile[32][33];
    size_t base = (size_t)blockIdx.z * T_SEQ * D_HEAD;
    int t0 = blockIdx.x * 32, d0 = blockIdx.y * 32;
    int tx = threadIdx.x, ty = threadIdx.y;
    for (int i = ty; i < 32; i += 8)
        tile[i][tx] = in[base + (size_t)(t0 + i) * D_HEAD + d0 + tx];
    __syncthreads();
    size_t tbase = base + (size_t)(t0 >> 6) * 4096 + (t0 & 32);
    for (int i = ty; i < 32; i += 8)
        out[tbase + (size_t)(d0 + i) * 64 + tx] = tile[tx][i];
}

// ---------------- LayerNorm (768 wide), fp32 in -> bf16 out ------------------
__global__ __launch_bounds__(256) void ln_kernel(const float* __restrict__ x,
                                                 const float* __restrict__ g,
                                                 const float* __restrict__ bta,
                                                 unsigned short* __restrict__ out) {
    int row = blockIdx.x;
    const float* xr = x + (size_t)row * D_EMB;
    int tid = threadIdx.x;
    float v[3];
    float s = 0.f, s2 = 0.f;
#pragma unroll
    for (int i = 0; i < 3; i++) {
        v[i] = xr[tid + i * 256];
        s += v[i];
        s2 += v[i] * v[i];
    }
#pragma unroll
    for (int o = 1; o < 64; o <<= 1) {
        s += __shfl_xor(s, o);
        s2 += __shfl_xor(s2, o);
    }
    __shared__ float red[8];
    int wave = tid >> 6, lane = tid & 63;
    if (lane == 0) { red[wave] = s; red[wave + 4] = s2; }
    __syncthreads();
    s = red[0] + red[1] + red[2] + red[3];
    s2 = red[4] + red[5] + red[6] + red[7];
    float mu = s * (1.f / 768.f);
    float var = s2 * (1.f / 768.f) - mu * mu;
    float rstd = rsqrtf(var + 1e-5f);
#pragma unroll
    for (int i = 0; i < 3; i++) {
        int c = tid + i * 256;
        out[(size_t)row * D_EMB + c] = f2bf((v[i] - mu) * rstd * g[c] + bta[c]);
    }
}

// ---------------- GEMM: C[M,N] = A[M,K] * Bt[N,K]^T, bf16 in, fp32 acc -------
// R7: PIPE flag. The wo/w2 launches (384 blocks = 1.5/CU, grid-limited
// occupancy, MfmaUtil 19%) are latency-bound: __syncthreads' vmcnt(0) drain
// costs ~1000cy/gstep vs ~400cy compute, nothing fills the stall. PIPE=true:
// 4 LDS buffers (64KB -- free, occupancy is grid-limited), prefetch distance
// 3, counted s_waitcnt vmcnt(8) + raw s_barrier; per-wave vmcnt covers its
// own tile-i loads, barrier broadcasts. Reuse distance 4 is race-free
// (readers pass lgkm waits before the barrier preceding the overwrite).
// qkv/w1 (5 blk/CU at 32KB) keep PIPE=false -- R5 showed 48KB LDS there
// costs more (5->3 blk/CU) than the pipeline gains.
template <int EPI, int MT, bool PIPE>
__global__ __launch_bounds__(256) void gemm_kernel(
    const unsigned short* __restrict__ A, const unsigned short* __restrict__ Bt, int K,
    int Nt, const float* __restrict__ bias, const float* __restrict__ resid,
    float* __restrict__ outF, unsigned short* __restrict__ outB,
    unsigned short* __restrict__ Qb, unsigned short* __restrict__ Kb,
    unsigned short* __restrict__ Vb) {
    constexpr int NAI = (MT == 128) ? 4 : 2;     // act M-subtiles per wave
    constexpr int NBUF = PIPE ? 4 : 2;
    __shared__ unsigned short As[NBUF][MT * 32];
    __shared__ unsigned short Bs[NBUF][4096];
    const int tid = threadIdx.x;
    const int wave = tid >> 6, lane = tid & 63;
    const int n16 = lane & 15, kq = lane >> 4;
    const int moff = (wave >> 1) * (MT / 2), noff = (wave & 1) * 64;
    // grid decode: (NTOK/MT)/8 M-tiles per XCD stripe; N inner
    const int id = blockIdx.x;
    const int xcd = id & 7, s = id >> 3;
    const int mt = xcd * (NTOK / MT / 8) + s / Nt, nt_ = s % Nt;
    const long m0 = (long)mt * MT, nb0 = (long)nt_ * 128;

    // staging thread-constants; source chunk sigma-permuted within each 64B row
    const int c0 = (wave * 2 + 0) * 64 + lane;   // B: 512 chunks, 2/thread
    const int c1 = (wave * 2 + 1) * 64 + lane;
    const int r0 = c0 >> 2, r1 = c1 >> 2;
    const unsigned short* bP0 = Bt + (nb0 + r0) * K + (((c0 & 3) ^ sg(r0)) << 3);
    const unsigned short* bP1 = Bt + (nb0 + r1) * K + (((c1 & 3) ^ sg(r1)) << 3);
    const int ca = (MT == 128) ? c0 : (wave * 64 + lane);  // A chunk index
    const int ra = ca >> 2;
    const unsigned short* aP0 = A + (m0 + ra) * K + (((ca & 3) ^ sg(ra)) << 3);
    const unsigned short* aP1 = (MT == 128)
        ? A + (m0 + r1) * K + (((c1 & 3) ^ sg(r1)) << 3) : nullptr;
    // fragment LDS short-indices (loop-invariant; sigma is 16-periodic)
    const int sn = sg(n16);
    const int fw = (noff + n16) * 32 + ((kq ^ sn) << 3);   // weight frags (Bs)
    const int fa = (moff + n16) * 32 + ((kq ^ sn) << 3);   // act frags (As)

    const v4f vzero = {0.f, 0.f, 0.f, 0.f};
    v4f acc[4][NAI];
#pragma unroll
    for (int wi = 0; wi < 4; wi++)
#pragma unroll
        for (int ai = 0; ai < NAI; ai++) acc[wi][ai] = vzero;

    auto stage = [&](int nb, int kpos) {
        unsigned short* asb = &As[0][0] + nb * (MT * 32);
        unsigned short* bsb = &Bs[0][0] + nb * 4096;
        if (MT == 128) {
            g2lds16(aP0 + kpos, asb + (wave * 2 + 0) * 512);
            g2lds16(aP1 + kpos, asb + (wave * 2 + 1) * 512);
        } else {
            g2lds16(aP0 + kpos, asb + wave * 512);  // chunks wave*64..+63
        }
        g2lds16(bP0 + kpos, bsb + (wave * 2 + 0) * 512);
        g2lds16(bP1 + kpos, bsb + (wave * 2 + 1) * 512);
    };
    auto compute = [&](int nb) {
        const unsigned short* asb = &As[0][0] + nb * (MT * 32);
        const unsigned short* bsb = &Bs[0][0] + nb * 4096;
        v8bf wf[4], af[NAI];
#pragma unroll
        for (int i = 0; i < 4; i++) wf[i] = *(const v8bf*)(bsb + fw + i * 512);
#pragma unroll
        for (int i = 0; i < NAI; i++) af[i] = *(const v8bf*)(asb + fa + i * 512);
#pragma unroll
        for (int wi = 0; wi < 4; wi++)
#pragma unroll
            for (int ai = 0; ai < NAI; ai++)
                acc[wi][ai] = __builtin_amdgcn_mfma_f32_16x16x32_bf16(wf[wi], af[ai],
                                                                     acc[wi][ai], 0, 0, 0);
    };

    if constexpr (PIPE) {
        // prologue: 3 tiles in flight (12 loads); tile i ready when vmcnt<=8
        stage(0, 0);
        stage(1, 32);
        stage(2, 64);
        const int nsteps = K / 32;
#pragma unroll 1
        for (int i = 0; i < nsteps - 3; i++) {
            asm volatile("s_waitcnt vmcnt(8)" ::: "memory");
            __builtin_amdgcn_s_barrier();
            __builtin_amdgcn_sched_barrier(0);
            stage((i + 3) & 3, (i + 3) * 32);
            compute(i & 3);
        }
        asm volatile("s_waitcnt vmcnt(8)" ::: "memory");
        __builtin_amdgcn_s_barrier();
        __builtin_amdgcn_sched_barrier(0);
        compute((nsteps - 3) & 3);
        asm volatile("s_waitcnt vmcnt(4)" ::: "memory");
        __builtin_amdgcn_s_barrier();
        __builtin_amdgcn_sched_barrier(0);
        compute((nsteps - 2) & 3);
        asm volatile("s_waitcnt vmcnt(0)" ::: "memory");
        __builtin_amdgcn_s_barrier();
        __builtin_amdgcn_sched_barrier(0);
        compute((nsteps - 1) & 3);
    } else {
        stage(0, 0);
#pragma unroll 1
        for (int k0 = 0; k0 < K; k0 += 64) {
            __syncthreads();
            stage(1, k0 + 32);
            compute(0);
            __syncthreads();
            if (k0 + 64 < K) stage(0, k0 + 64);
            compute(1);
        }
    }

#pragma unroll
    for (int wi = 0; wi < 4; wi++) {
#pragma unroll
        for (int ai = 0; ai < NAI; ai++) {
            const long Nb = nb0 + noff + wi * 16 + kq * 4;
            const long M = m0 + moff + ai * 16 + n16;
            if (EPI == 0) {
                int which = (int)(Nb / 768);
                int c = (int)(Nb - which * 768);
                int hh = c >> 6, ii = c & 63;
                int bb = (int)(M >> 12), t = (int)(M & 4095);
                size_t dst = (((size_t)bb * N_HEAD + hh) * T_SEQ + t) * D_HEAD + ii;
                union { uint2 u2; unsigned short us[4]; } pk;
#pragma unroll
                for (int r = 0; r < 4; r++) {
                    float v = acc[wi][ai][r];
                    if (which == 0) v *= QSCALE;
                    pk.us[r] = f2bf(v);
                }
                if (which == 0) *(uint2*)(&Qb[dst]) = pk.u2;
                else if (which == 1) *(uint2*)(&Kb[dst]) = pk.u2;
                else *(uint2*)(&Vb[dst]) = pk.u2;
            } else if (EPI == 1) {
                float4 b4 = *(const float4*)(&bias[Nb]);
                float4 r4 = *(const float4*)(&resid[M * 768 + Nb]);
                float4 o4;
                o4.x = acc[wi][ai][0] + b4.x + r4.x;
                o4.y = acc[wi][ai][1] + b4.y + r4.y;
                o4.z = acc[wi][ai][2] + b4.z + r4.z;
                o4.w = acc[wi][ai][3] + b4.w + r4.w;
                *(float4*)(&outF[M * 768 + Nb]) = o4;
            } else {
                float4 b4 = *(const float4*)(&bias[Nb]);
                union { uint2 u2; unsigned short us[4]; } pk;
#pragma unroll
                for (int r = 0; r < 4; r++) {
                    float t = acc[wi][ai][r] + ((const float*)&b4)[r];
                    // tanh-form GELU via exp2+rcp (~7 VALU vs erff ~40);
                    // max err ~3e-4 << bf16 quantum of the stored output
                    float y = t * (-2.302118131f + t * t * -0.1029433585f);
                    float gl = t * fastrcp(1.f + __builtin_amdgcn_exp2f(y));
                    pk.us[r] = f2bf(gl);
                }
                *(uint2*)(&outB[M * 3072 + Nb]) = pk.u2;
            }
        }
    }
}

// ---------------- Flash attention (causal), bf16 Q/K/Vt -> bf16 y ------------
// UNPAIRED blocks -- 1536 blocks (24 bh x 64 q-tiles), longest-qt-first within
// each XCD stripe; 4-5 resident blocks/CU. S^T trick, pre-scaled Q, l via
// ones-MFMA, unroll-2 dbuf K/V staging, P in registers via permlane32/16_swap
// -> exact K32 A-frags (0 conflicts), setprio around MFMA clusters.
__global__ __launch_bounds__(256) void attn_kernel(const unsigned short* __restrict__ Q,
                                                   const unsigned short* __restrict__ Kg,
                                                   const unsigned short* __restrict__ Vt,
                                                   unsigned short* __restrict__ y) {
    __shared__ unsigned short Kt[2][4096];
    __shared__ unsigned short Vl[2][4096];
    const int tid = threadIdx.x;
    const int wave = tid >> 6, lane = tid & 63;
    const int n16 = lane & 15, kq = lane >> 4;
    const int id = blockIdx.x;
    const int xcd = id & 7, slot = id >> 3;           // slot 0..191
    const int combo = xcd * 3 + (slot % 3);           // 3 bh-combos per XCD
    const int qt = 63 - slot / 3;                     // longest blocks first
    const int h = combo % N_HEAD, b = combo / N_HEAD;
    const size_t hoff = (((size_t)b * N_HEAD + h) * T_SEQ) * D_HEAD;
    const unsigned short* Qh = Q + hoff;
    const unsigned short* Kh = Kg + hoff;   // [t][64], k-tile contiguous 8KB
    const unsigned short* Vh = Vt + hoff;   // [kt][64][64] tiled
    const v4f vzero = {0.f, 0.f, 0.f, 0.f};

    const int sC0 = (wave * 2 + 0) * 64 + lane;
    const int sC1 = (wave * 2 + 1) * 64 + lane;
    const int soff0 = (sC0 >> 3) * 64 + ((((sC0 & 7) ^ ((sC0 >> 3) & 7))) << 3);
    const int soff1 = (sC1 >> 3) * 64 + ((((sC1 & 7) ^ ((sC1 >> 3) & 7))) << 3);
    const int fb0 = n16 * 64 + ((kq ^ (n16 & 7)) << 3);
    const int fb1 = n16 * 64 + (((4 + kq) ^ (n16 & 7)) << 3);
    v8bf vone;
#pragma unroll
    for (int j = 0; j < 8; j++) ((unsigned short*)&vone)[j] = 0x3F80;  // bf16 1.0

    const int qglob = qt * 64 + wave * 16 + n16;
    v8bf qf[2];
#pragma unroll
    for (int ks = 0; ks < 2; ks++)
        qf[ks] = *(const v8bf*)(&Qh[(size_t)qglob * D_HEAD + ks * 32 + kq * 8]);

    v4f o[4], lacc;
#pragma unroll
    for (int nt = 0; nt < 4; nt++) o[nt] = vzero;
    lacc = vzero;

    const unsigned short* knext;
    const unsigned short* vnext;

    auto step = [&](auto BUFC, int kt, bool pref, bool diag) {
        constexpr int buf = decltype(BUFC)::value;
        __syncthreads();  // buf's tiles ready (vmcnt), prev reads done (lgkm)
        if (pref) {
            g2lds16(knext + soff0, &Kt[buf ^ 1][(wave * 2 + 0) * 512]);
            g2lds16(knext + soff1, &Kt[buf ^ 1][(wave * 2 + 1) * 512]);
            g2lds16(vnext + soff0, &Vl[buf ^ 1][(wave * 2 + 0) * 512]);
            g2lds16(vnext + soff1, &Vl[buf ^ 1][(wave * 2 + 1) * 512]);
            knext += 4096;
            vnext += 4096;
        }
        v4f s[4];
#pragma unroll
        for (int nt = 0; nt < 4; nt++) s[nt] = vzero;
        __builtin_amdgcn_s_setprio(1);
#pragma unroll
        for (int nt = 0; nt < 4; nt++) {
            v8bf k0 = *(const v8bf*)(&Kt[buf][nt * 1024 + fb0]);
            v8bf k1 = *(const v8bf*)(&Kt[buf][nt * 1024 + fb1]);
            s[nt] = __builtin_amdgcn_mfma_f32_16x16x32_bf16(k0, qf[0], s[nt], 0, 0, 0);
            s[nt] = __builtin_amdgcn_mfma_f32_16x16x32_bf16(k1, qf[1], s[nt], 0, 0, 0);
        }
        __builtin_amdgcn_s_setprio(0);
        // exp2 + bf16 pack; pa[ntk] = P[keys ntk*16+4kq..+3][q=n16]
        union PW { v4s s4; unsigned u[2]; } pa[4];
#pragma unroll
        for (int ntk = 0; ntk < 4; ntk++) {
            union { v4s s4; __bf16 h[4]; } pk;
#pragma unroll
            for (int r = 0; r < 4; r++) {
                float p = __builtin_amdgcn_exp2f(s[ntk][r]);
                if (diag) {
                    int key = kt * 64 + ntk * 16 + kq * 4 + r;
                    if (key > qglob) p = 0.f;
                }
                pk.h[r] = (__bf16)p;
            }
            pa[ntk].s4 = pk.s4;
        }
        // permlane exchange: build K32 A-frags pf[ks] (lane: P^T[q=n16]
        // [keys ks*32+kq*8..+7]). For word j: 32swap gathers {u01,v01}/{u23,v23},
        // 16swap gathers even/odd rows -> W_j and W_{j+2}.
        union F8 { v8bf v; unsigned u[4]; } pf[2];
#pragma unroll
        for (int ks = 0; ks < 2; ks++) {
#pragma unroll
            for (int j = 0; j < 2; j++) {
                unsigned X = pa[2 * ks].u[j], Y = pa[2 * ks + 1].u[j];
                pl32swap(X, Y);
                pl16swap(X, Y);
                pf[ks].u[j] = X;
                pf[ks].u[j + 2] = Y;
            }
        }
        __builtin_amdgcn_s_setprio(1);
#pragma unroll
        for (int ks = 0; ks < 2; ks++) {
            lacc = __builtin_amdgcn_mfma_f32_16x16x32_bf16(pf[ks].v, vone, lacc, 0, 0, 0);
#pragma unroll
            for (int nt = 0; nt < 4; nt++) {
                v8bf vb = *(const v8bf*)(&Vl[buf][nt * 1024 + (ks ? fb1 : fb0)]);
                o[nt] = __builtin_amdgcn_mfma_f32_16x16x32_bf16(pf[ks].v, vb, o[nt], 0, 0, 0);
            }
        }
        __builtin_amdgcn_s_setprio(0);
    };

    // prologue: stage kt=0 into buf0 (first step's barrier drains vmcnt)
    g2lds16(Kh + soff0, &Kt[0][(wave * 2 + 0) * 512]);
    g2lds16(Kh + soff1, &Kt[0][(wave * 2 + 1) * 512]);
    g2lds16(Vh + soff0, &Vl[0][(wave * 2 + 0) * 512]);
    g2lds16(Vh + soff1, &Vl[0][(wave * 2 + 1) * 512]);
    knext = Kh + 4096;
    vnext = Vh + 4096;

    int kt = 0;
#pragma unroll 1
    while (kt + 2 <= qt) {
        step(IC<0>{}, kt, true, false);
        step(IC<1>{}, kt + 1, true, false);
        kt += 2;
    }
    if (kt < qt) {
        step(IC<0>{}, kt, true, false);
        step(IC<1>{}, kt + 1, false, true);
    } else {
        step(IC<0>{}, kt, false, true);
    }

    float linv[4];
#pragma unroll
    for (int r = 0; r < 4; r++) linv[r] = fastrcp(lacc[r]);
#pragma unroll
    for (int nt = 0; nt < 4; nt++)
#pragma unroll
        for (int r = 0; r < 4; r++) {
            int q = qt * 64 + wave * 16 + kq * 4 + r;
            float val = o[nt][r] * linv[r];
            y[((size_t)b * T_SEQ + q) * D_EMB + h * 64 + nt * 16 + n16] = f2bf(val);
        }
}

// ---------------- launch -----------------------------------------------------
extern "C" void kernel_launch(void* const* d_in, const int* in_sizes, int n_in,
                              void* d_out, int out_size, void* d_ws, size_t ws_size,
                              hipStream_t stream) {
    const float* x = (const float*)d_in[0];
    const float* ln1_g = (const float*)d_in[1];
    const float* ln1_b = (const float*)d_in[2];
    const float* wqkv_w = (const float*)d_in[3];
    const float* wo_w = (const float*)d_in[4];
    const float* wo_b = (const float*)d_in[5];
    const float* ln2_g = (const float*)d_in[6];
    const float* ln2_b = (const float*)d_in[7];
    const float* w1_w = (const float*)d_in[8];
    const float* w1_b = (const float*)d_in[9];
    const float* w2_w = (const float*)d_in[10];
    const float* w2_b = (const float*)d_in[11];
    float* out = (float*)d_out;

    char* ws = (char*)d_ws;
    size_t off = 0;
    auto alloc = [&](size_t bytes) -> void* {
        void* p = ws + off;
        off += (bytes + 255) & ~(size_t)255;
        return p;
    };
    unsigned short* xn = (unsigned short*)alloc((size_t)NTOK * D_EMB * 2);
    unsigned short* wqkvT = (unsigned short*)alloc((size_t)2304 * 768 * 2);
    unsigned short* woT = (unsigned short*)alloc((size_t)768 * 768 * 2);
    unsigned short* w1T = (unsigned short*)alloc((size_t)3072 * 768 * 2);
    unsigned short* w2T = (unsigned short*)alloc((size_t)768 * 3072 * 2);
    unsigned short* Qb = (unsigned short*)alloc((size_t)NTOK * D_EMB * 2);
    unsigned short* Kb = (unsigned short*)alloc((size_t)NTOK * D_EMB * 2);
    unsigned short* Vb = (unsigned short*)alloc((size_t)NTOK * D_EMB * 2);
    unsigned short* yb = (unsigned short*)alloc((size_t)NTOK * D_EMB * 2);
    float* res1 = (float*)alloc((size_t)NTOK * D_EMB * 4);
    unsigned short* Vtb = xn;   // V^T overlay: xn dead during attn
    unsigned short* hbuf = Qb;  // w1 out overlay: spans Qb..yb (all dead then)

    dim3 tb(32, 8);
    tcast_kernel<<<dim3(2304 / 32, 768 / 32), tb, 0, stream>>>(wqkv_w, wqkvT, 768, 2304);
    tcast_kernel<<<dim3(768 / 32, 768 / 32), tb, 0, stream>>>(wo_w, woT, 768, 768);
    tcast_kernel<<<dim3(3072 / 32, 768 / 32), tb, 0, stream>>>(w1_w, w1T, 768, 3072);
    tcast_kernel<<<dim3(768 / 32, 3072 / 32), tb, 0, stream>>>(w2_w, w2T, 3072, 768);

    ln_kernel<<<NTOK, 256, 0, stream>>>(x, ln1_g, ln1_b, xn);

    gemm_kernel<0, 128, false><<<1152, 256, 0, stream>>>(  // 32KB LDS, 5/CU
        xn, wqkvT, 768, 18, nullptr, nullptr, nullptr, nullptr, Qb, Kb, Vb);

    vtrans_kernel<<<dim3(T_SEQ / 32, 2, 2 * N_HEAD), tb, 0, stream>>>(Vb, Vtb);

    attn_kernel<<<1536, 256, 0, stream>>>(Qb, Kb, Vtb, yb);

    gemm_kernel<1, 128, true><<<384, 256, 0, stream>>>(    // PIPE: 64KB, depth-3
        yb, woT, 768, 6, wo_b, x, res1, nullptr, nullptr, nullptr, nullptr);

    ln_kernel<<<NTOK, 256, 0, stream>>>(res1, ln2_g, ln2_b, xn);

    gemm_kernel<2, 128, false><<<1536, 256, 0, stream>>>(  // 32KB LDS, 5/CU
        xn, w1T, 768, 24, w1_b, nullptr, nullptr, hbuf, nullptr, nullptr, nullptr);

    gemm_kernel<1, 128, true><<<384, 256, 0, stream>>>(    // PIPE: 64KB, depth-3
        hbuf, w2T, 3072, 6, w2_b, res1, out, nullptr, nullptr, nullptr, nullptr);
}

// Round 8
// 412.467 us; speedup vs baseline: 1.1466x; 1.1466x over previous
//
#include <hip/hip_runtime.h>

#define T_SEQ 4096
#define D_EMB 768
#define N_HEAD 12
#define D_HEAD 64
#define D_MLP 3072
#define NTOK 8192   // B*T
#define QSCALE 0.18033688011112043f  // log2(e)/8, folded into Q at qkv epilogue

typedef __bf16 v8bf __attribute__((ext_vector_type(8)));
typedef float v4f __attribute__((ext_vector_type(4)));
typedef short v4s __attribute__((ext_vector_type(4)));
typedef unsigned v2u __attribute__((ext_vector_type(2)));

template <int N> struct IC { static constexpr int value = N; };

__device__ __forceinline__ unsigned short f2bf(float f) {
    unsigned int u = __float_as_uint(f);
    unsigned int r = (u + 0x7fffu + ((u >> 16) & 1u)) >> 16;
    return (unsigned short)r;
}

__device__ __forceinline__ void g2lds16(const void* g, void* l) {
    __builtin_amdgcn_global_load_lds(
        (const __attribute__((address_space(1))) void*)g,
        (__attribute__((address_space(3))) void*)l, 16, 0, 0);
}

__device__ __forceinline__ float fastrcp(float x) {
#if __has_builtin(__builtin_amdgcn_rcpf)
    return __builtin_amdgcn_rcpf(x);
#else
    return 1.f / x;
#endif
}

// row-swap primitives (gfx950): 32-swap gathers half-pairs, 16-swap gathers
// even/odd 16-rows. Composed they turn the S^T C/D layout into exact K32
// A-fragments -- zero LDS traffic, full-rate VALU.
__device__ __forceinline__ void pl32swap(unsigned& a, unsigned& b) {
#if __has_builtin(__builtin_amdgcn_permlane32_swap)
    v2u r = __builtin_amdgcn_permlane32_swap(a, b, false, false);
    a = r[0]; b = r[1];
#else
    asm volatile("v_permlane32_swap_b32 %0, %1" : "+v"(a), "+v"(b));
#endif
}
__device__ __forceinline__ void pl16swap(unsigned& a, unsigned& b) {
#if __has_builtin(__builtin_amdgcn_permlane16_swap)
    v2u r = __builtin_amdgcn_permlane16_swap(a, b, false, false);
    a = r[0]; b = r[1];
#else
    asm volatile("v_permlane16_swap_b32 %0, %1" : "+v"(a), "+v"(b));
#endif
}

// chunk swizzle for 32-short (4x16B) LDS rows: 16-periodic, makes frag reads
// <=2-way bank-aliased (free) instead of 8-way (2.9x, m136)
__device__ __forceinline__ int sg(int r) { return (r ^ (r >> 2)) & 3; }

// ---------------- weight cast + transpose: fp32 [K][N] -> bf16 [N][K] --------
__global__ void tcast_kernel(const float* __restrict__ in, unsigned short* __restrict__ out,
                             int K, int N) {
    __shared__ float tile[32][33];
    int k0 = blockIdx.y * 32, n0 = blockIdx.x * 32;
    int tx = threadIdx.x, ty = threadIdx.y;
    for (int i = ty; i < 32; i += 8)
        tile[i][tx] = in[(size_t)(k0 + i) * N + n0 + tx];
    __syncthreads();
    for (int i = ty; i < 32; i += 8)
        out[(size_t)(n0 + i) * K + k0 + tx] = f2bf(tile[tx][i]);
}

// ------- V transpose, TILED: [bh][t][64] -> [bh][kt][64d][64k] (8KB tiles) ---
__global__ void vtrans_kernel(const unsigned short* __restrict__ in,
                              unsigned short* __restrict__ out) {
    __shared__ unsigned short tile[32][33];
    size_t base = (size_t)blockIdx.z * T_SEQ * D_HEAD;
    int t0 = blockIdx.x * 32, d0 = blockIdx.y * 32;
    int tx = threadIdx.x, ty = threadIdx.y;
    for (int i = ty; i < 32; i += 8)
        tile[i][tx] = in[base + (size_t)(t0 + i) * D_HEAD + d0 + tx];
    __syncthreads();
    size_t tbase = base + (size_t)(t0 >> 6) * 4096 + (t0 & 32);
    for (int i = ty; i < 32; i += 8)
        out[tbase + (size_t)(d0 + i) * 64 + tx] = tile[tx][i];
}

// ---------------- LayerNorm (768 wide), fp32 in -> bf16 out ------------------
__global__ __launch_bounds__(256) void ln_kernel(const float* __restrict__ x,
                                                 const float* __restrict__ g,
                                                 const float* __restrict__ bta,
                                                 unsigned short* __restrict__ out) {
    int row = blockIdx.x;
    const float* xr = x + (size_t)row * D_EMB;
    int tid = threadIdx.x;
    float v[3];
    float s = 0.f, s2 = 0.f;
#pragma unroll
    for (int i = 0; i < 3; i++) {
        v[i] = xr[tid + i * 256];
        s += v[i];
        s2 += v[i] * v[i];
    }
#pragma unroll
    for (int o = 1; o < 64; o <<= 1) {
        s += __shfl_xor(s, o);
        s2 += __shfl_xor(s2, o);
    }
    __shared__ float red[8];
    int wave = tid >> 6, lane = tid & 63;
    if (lane == 0) { red[wave] = s; red[wave + 4] = s2; }
    __syncthreads();
    s = red[0] + red[1] + red[2] + red[3];
    s2 = red[4] + red[5] + red[6] + red[7];
    float mu = s * (1.f / 768.f);
    float var = s2 * (1.f / 768.f) - mu * mu;
    float rstd = rsqrtf(var + 1e-5f);
#pragma unroll
    for (int i = 0; i < 3; i++) {
        int c = tid + i * 256;
        out[(size_t)row * D_EMB + c] = f2bf((v[i] - mu) * rstd * g[c] + bta[c]);
    }
}

// ---------------- GEMM: C[M,N] = A[M,K] * Bt[N,K]^T, bf16 in, fp32 acc -------
// R6-exact (R8 reverted R7's runtime-indexed buffers -- they broke the
// compiler's immediate-offset ds_read folding). Swapped-operand MFMA, dbuf
// global_load_lds staging, XCD-striped 1-D grid, sigma-swizzled LDS chunks.
template <int EPI, int MT>
__global__ __launch_bounds__(256) void gemm_kernel(
    const unsigned short* __restrict__ A, const unsigned short* __restrict__ Bt, int K,
    int Nt, const float* __restrict__ bias, const float* __restrict__ resid,
    float* __restrict__ outF, unsigned short* __restrict__ outB,
    unsigned short* __restrict__ Qb, unsigned short* __restrict__ Kb,
    unsigned short* __restrict__ Vb) {
    constexpr int NAI = (MT == 128) ? 4 : 2;     // act M-subtiles per wave
    __shared__ unsigned short As[2][MT * 32];
    __shared__ unsigned short Bs[2][4096];
    const int tid = threadIdx.x;
    const int wave = tid >> 6, lane = tid & 63;
    const int n16 = lane & 15, kq = lane >> 4;
    const int moff = (wave >> 1) * (MT / 2), noff = (wave & 1) * 64;
    // grid decode: (NTOK/MT)/8 M-tiles per XCD stripe; N inner
    const int id = blockIdx.x;
    const int xcd = id & 7, s = id >> 3;
    const int mt = xcd * (NTOK / MT / 8) + s / Nt, nt_ = s % Nt;
    const long m0 = (long)mt * MT, nb0 = (long)nt_ * 128;

    // staging thread-constants; source chunk sigma-permuted within each 64B row
    const int c0 = (wave * 2 + 0) * 64 + lane;   // B: 512 chunks, 2/thread
    const int c1 = (wave * 2 + 1) * 64 + lane;
    const int r0 = c0 >> 2, r1 = c1 >> 2;
    const unsigned short* bP0 = Bt + (nb0 + r0) * K + (((c0 & 3) ^ sg(r0)) << 3);
    const unsigned short* bP1 = Bt + (nb0 + r1) * K + (((c1 & 3) ^ sg(r1)) << 3);
    const int ca = (MT == 128) ? c0 : (wave * 64 + lane);  // A chunk index
    const int ra = ca >> 2;
    const unsigned short* aP0 = A + (m0 + ra) * K + (((ca & 3) ^ sg(ra)) << 3);
    const unsigned short* aP1 = (MT == 128)
        ? A + (m0 + r1) * K + (((c1 & 3) ^ sg(r1)) << 3) : nullptr;
    // fragment LDS short-indices (loop-invariant; sigma is 16-periodic)
    const int sn = sg(n16);
    const int fw = (noff + n16) * 32 + ((kq ^ sn) << 3);   // weight frags (Bs)
    const int fa = (moff + n16) * 32 + ((kq ^ sn) << 3);   // act frags (As)

    const v4f vzero = {0.f, 0.f, 0.f, 0.f};
    v4f acc[4][NAI];
#pragma unroll
    for (int wi = 0; wi < 4; wi++)
#pragma unroll
        for (int ai = 0; ai < NAI; ai++) acc[wi][ai] = vzero;

    auto stage = [&](auto BUFC, int kpos) {
        constexpr int nb = decltype(BUFC)::value;
        if (MT == 128) {
            g2lds16(aP0 + kpos, &As[nb][(wave * 2 + 0) * 512]);
            g2lds16(aP1 + kpos, &As[nb][(wave * 2 + 1) * 512]);
        } else {
            g2lds16(aP0 + kpos, &As[nb][wave * 512]);  // chunks wave*64..+63
        }
        g2lds16(bP0 + kpos, &Bs[nb][(wave * 2 + 0) * 512]);
        g2lds16(bP1 + kpos, &Bs[nb][(wave * 2 + 1) * 512]);
    };
    auto gstep = [&](auto BUFC, int kpos, bool pref) {
        constexpr int buf = decltype(BUFC)::value;
        __syncthreads();
        if (pref) stage(IC<buf ^ 1>{}, kpos + 32);
        v8bf wf[4], af[NAI];
#pragma unroll
        for (int i = 0; i < 4; i++) wf[i] = *(const v8bf*)(&Bs[buf][fw + i * 512]);
#pragma unroll
        for (int i = 0; i < NAI; i++) af[i] = *(const v8bf*)(&As[buf][fa + i * 512]);
#pragma unroll
        for (int wi = 0; wi < 4; wi++)
#pragma unroll
            for (int ai = 0; ai < NAI; ai++)
                acc[wi][ai] = __builtin_amdgcn_mfma_f32_16x16x32_bf16(wf[wi], af[ai],
                                                                     acc[wi][ai], 0, 0, 0);
    };

    stage(IC<0>{}, 0);
#pragma unroll 1
    for (int k0 = 0; k0 < K; k0 += 64) {
        gstep(IC<0>{}, k0, true);
        gstep(IC<1>{}, k0 + 32, k0 + 64 < K);
    }

#pragma unroll
    for (int wi = 0; wi < 4; wi++) {
#pragma unroll
        for (int ai = 0; ai < NAI; ai++) {
            const long Nb = nb0 + noff + wi * 16 + kq * 4;
            const long M = m0 + moff + ai * 16 + n16;
            if (EPI == 0) {
                int which = (int)(Nb / 768);
                int c = (int)(Nb - which * 768);
                int hh = c >> 6, ii = c & 63;
                int bb = (int)(M >> 12), t = (int)(M & 4095);
                size_t dst = (((size_t)bb * N_HEAD + hh) * T_SEQ + t) * D_HEAD + ii;
                union { uint2 u2; unsigned short us[4]; } pk;
#pragma unroll
                for (int r = 0; r < 4; r++) {
                    float v = acc[wi][ai][r];
                    if (which == 0) v *= QSCALE;
                    pk.us[r] = f2bf(v);
                }
                if (which == 0) *(uint2*)(&Qb[dst]) = pk.u2;
                else if (which == 1) *(uint2*)(&Kb[dst]) = pk.u2;
                else *(uint2*)(&Vb[dst]) = pk.u2;
            } else if (EPI == 1) {
                float4 b4 = *(const float4*)(&bias[Nb]);
                float4 r4 = *(const float4*)(&resid[M * 768 + Nb]);
                float4 o4;
                o4.x = acc[wi][ai][0] + b4.x + r4.x;
                o4.y = acc[wi][ai][1] + b4.y + r4.y;
                o4.z = acc[wi][ai][2] + b4.z + r4.z;
                o4.w = acc[wi][ai][3] + b4.w + r4.w;
                *(float4*)(&outF[M * 768 + Nb]) = o4;
            } else {
                float4 b4 = *(const float4*)(&bias[Nb]);
                union { uint2 u2; unsigned short us[4]; } pk;
#pragma unroll
                for (int r = 0; r < 4; r++) {
                    float t = acc[wi][ai][r] + ((const float*)&b4)[r];
                    // tanh-form GELU via exp2+rcp (~7 VALU vs erff ~40);
                    // max err ~3e-4 << bf16 quantum of the stored output
                    float y = t * (-2.302118131f + t * t * -0.1029433585f);
                    float gl = t * fastrcp(1.f + __builtin_amdgcn_exp2f(y));
                    pk.us[r] = f2bf(gl);
                }
                *(uint2*)(&outB[M * 3072 + Nb]) = pk.u2;
            }
        }
    }
}

// -------- split-K GEMM for thin-N (wo/w2): 512 thr, 2 K-groups, EPI=1 --------
// R8: wo/w2 (grid 384 = 1.5 blk/CU) are bound by a fixed ~2000cy per-step
// serial latency hidden only by independent 4-wave chains (R4/R6/R7 all land
// at steps/CU x 2000/n). Same tile + same grid, but waves 0-3 do K-half 0 and
// waves 4-7 K-half 1 concurrently (own LDS staging, 64KB) -> steps/block
// halve, chains/CU double: 144 steps/CU at n=3 -> ~40us predicted for w2.
// Group-1 accs pass through the dead staging LDS (exactly 4096 v4f); group-0
// adds + runs the bias+resid epilogue.
__global__ __launch_bounds__(512, 4) void gemm_splitk_kernel(
    const unsigned short* __restrict__ A, const unsigned short* __restrict__ Bt, int K,
    int Nt, const float* __restrict__ bias, const float* __restrict__ resid,
    float* __restrict__ outF) {
    __shared__ __align__(16) unsigned short SH[32768];   // 64KB
    const int tid = threadIdx.x;
    const int wave = tid >> 6, lane = tid & 63;
    const int kg = wave >> 2, wv = wave & 3;
    const int n16 = lane & 15, kq = lane >> 4;
    const int moff = (wv >> 1) * 64, noff = (wv & 1) * 64;
    const int id = blockIdx.x;
    const int xcd = id & 7, s = id >> 3;
    const int mt = xcd * (NTOK / 128 / 8) + s / Nt, nt_ = s % Nt;
    const long m0 = (long)mt * 128, nb0 = (long)nt_ * 128;
    const int Kh = K >> 1;

    const int c0 = (wv * 2 + 0) * 64 + lane;
    const int c1 = (wv * 2 + 1) * 64 + lane;
    const int r0 = c0 >> 2, r1 = c1 >> 2;
    const int kb = kg * Kh;
    const unsigned short* bP0 = Bt + (nb0 + r0) * K + ((((c0 & 3) ^ sg(r0)) << 3) + kb);
    const unsigned short* bP1 = Bt + (nb0 + r1) * K + ((((c1 & 3) ^ sg(r1)) << 3) + kb);
    const unsigned short* aP0 = A + (m0 + r0) * K + ((((c0 & 3) ^ sg(r0)) << 3) + kb);
    const unsigned short* aP1 = A + (m0 + r1) * K + ((((c1 & 3) ^ sg(r1)) << 3) + kb);
    const int sn = sg(n16);
    const int fw = (noff + n16) * 32 + ((kq ^ sn) << 3);
    const int fa = (moff + n16) * 32 + ((kq ^ sn) << 3);
    // LDS carve (short idx): A(kg,buf) @ (kg*2+buf)*4096; B(kg,buf) @ 16384+...
    const int abase = kg * 8192, bbase = 16384 + kg * 8192;

    const v4f vzero = {0.f, 0.f, 0.f, 0.f};
    v4f acc[4][4];
#pragma unroll
    for (int wi = 0; wi < 4; wi++)
#pragma unroll
        for (int ai = 0; ai < 4; ai++) acc[wi][ai] = vzero;

    auto stage = [&](auto BUFC, int kpos) {
        constexpr int nb = decltype(BUFC)::value;
        unsigned short* asb = SH + abase + nb * 4096;
        unsigned short* bsb = SH + bbase + nb * 4096;
        g2lds16(aP0 + kpos, asb + (wv * 2 + 0) * 512);
        g2lds16(aP1 + kpos, asb + (wv * 2 + 1) * 512);
        g2lds16(bP0 + kpos, bsb + (wv * 2 + 0) * 512);
        g2lds16(bP1 + kpos, bsb + (wv * 2 + 1) * 512);
    };
    auto gstep = [&](auto BUFC, int kpos, bool pref) {
        constexpr int buf = decltype(BUFC)::value;
        __syncthreads();
        if (pref) stage(IC<buf ^ 1>{}, kpos + 32);
        const unsigned short* asb = SH + abase + buf * 4096;
        const unsigned short* bsb = SH + bbase + buf * 4096;
        v8bf wf[4], af[4];
#pragma unroll
        for (int i = 0; i < 4; i++) wf[i] = *(const v8bf*)(bsb + fw + i * 512);
#pragma unroll
        for (int i = 0; i < 4; i++) af[i] = *(const v8bf*)(asb + fa + i * 512);
#pragma unroll
        for (int wi = 0; wi < 4; wi++)
#pragma unroll
            for (int ai = 0; ai < 4; ai++)
                acc[wi][ai] = __builtin_amdgcn_mfma_f32_16x16x32_bf16(wf[wi], af[ai],
                                                                     acc[wi][ai], 0, 0, 0);
    };

    stage(IC<0>{}, 0);
#pragma unroll 1
    for (int k0 = 0; k0 < Kh; k0 += 64) {
        gstep(IC<0>{}, k0, true);
        gstep(IC<1>{}, k0 + 32, k0 + 64 < Kh);
    }

    // cross-group reduction through the (now dead) staging LDS: 4096 v4f = 64KB
    __syncthreads();                       // all frag reads of SH done
    v4f* ex = (v4f*)SH;
    if (kg == 1) {
#pragma unroll
        for (int wi = 0; wi < 4; wi++)
#pragma unroll
            for (int ai = 0; ai < 4; ai++)
                ex[((wv * 16 + wi * 4 + ai) << 6) + lane] = acc[wi][ai];
    }
    __syncthreads();
    if (kg == 1) return;

#pragma unroll
    for (int wi = 0; wi < 4; wi++) {
#pragma unroll
        for (int ai = 0; ai < 4; ai++) {
            v4f p = ex[((wv * 16 + wi * 4 + ai) << 6) + lane];
            const long Nb = nb0 + noff + wi * 16 + kq * 4;
            const long M = m0 + moff + ai * 16 + n16;
            float4 b4 = *(const float4*)(&bias[Nb]);
            float4 r4 = *(const float4*)(&resid[M * 768 + Nb]);
            float4 o4;
            o4.x = acc[wi][ai][0] + p[0] + b4.x + r4.x;
            o4.y = acc[wi][ai][1] + p[1] + b4.y + r4.y;
            o4.z = acc[wi][ai][2] + p[2] + b4.z + r4.z;
            o4.w = acc[wi][ai][3] + p[3] + b4.w + r4.w;
            *(float4*)(&outF[M * 768 + Nb]) = o4;
        }
    }
}

// ---------------- Flash attention (causal), bf16 Q/K/Vt -> bf16 y ------------
// UNPAIRED blocks -- 1536 blocks (24 bh x 64 q-tiles), longest-qt-first within
// each XCD stripe; 4-5 resident blocks/CU. S^T trick, pre-scaled Q, l via
// ones-MFMA, unroll-2 dbuf K/V staging, P in registers via permlane32/16_swap
// -> exact K32 A-frags (0 conflicts), setprio around MFMA clusters.
__global__ __launch_bounds__(256) void attn_kernel(const unsigned short* __restrict__ Q,
                                                   const unsigned short* __restrict__ Kg,
                                                   const unsigned short* __restrict__ Vt,
                                                   unsigned short* __restrict__ y) {
    __shared__ unsigned short Kt[2][4096];
    __shared__ unsigned short Vl[2][4096];
    const int tid = threadIdx.x;
    const int wave = tid >> 6, lane = tid & 63;
    const int n16 = lane & 15, kq = lane >> 4;
    const int id = blockIdx.x;
    const int xcd = id & 7, slot = id >> 3;           // slot 0..191
    const int combo = xcd * 3 + (slot % 3);           // 3 bh-combos per XCD
    const int qt = 63 - slot / 3;                     // longest blocks first
    const int h = combo % N_HEAD, b = combo / N_HEAD;
    const size_t hoff = (((size_t)b * N_HEAD + h) * T_SEQ) * D_HEAD;
    const unsigned short* Qh = Q + hoff;
    const unsigned short* Kh = Kg + hoff;   // [t][64], k-tile contiguous 8KB
    const unsigned short* Vh = Vt + hoff;   // [kt][64][64] tiled
    const v4f vzero = {0.f, 0.f, 0.f, 0.f};

    const int sC0 = (wave * 2 + 0) * 64 + lane;
    const int sC1 = (wave * 2 + 1) * 64 + lane;
    const int soff0 = (sC0 >> 3) * 64 + ((((sC0 & 7) ^ ((sC0 >> 3) & 7))) << 3);
    const int soff1 = (sC1 >> 3) * 64 + ((((sC1 & 7) ^ ((sC1 >> 3) & 7))) << 3);
    const int fb0 = n16 * 64 + ((kq ^ (n16 & 7)) << 3);
    const int fb1 = n16 * 64 + (((4 + kq) ^ (n16 & 7)) << 3);
    v8bf vone;
#pragma unroll
    for (int j = 0; j < 8; j++) ((unsigned short*)&vone)[j] = 0x3F80;  // bf16 1.0

    const int qglob = qt * 64 + wave * 16 + n16;
    v8bf qf[2];
#pragma unroll
    for (int ks = 0; ks < 2; ks++)
        qf[ks] = *(const v8bf*)(&Qh[(size_t)qglob * D_HEAD + ks * 32 + kq * 8]);

    v4f o[4], lacc;
#pragma unroll
    for (int nt = 0; nt < 4; nt++) o[nt] = vzero;
    lacc = vzero;

    const unsigned short* knext;
    const unsigned short* vnext;

    auto step = [&](auto BUFC, int kt, bool pref, bool diag) {
        constexpr int buf = decltype(BUFC)::value;
        __syncthreads();  // buf's tiles ready (vmcnt), prev reads done (lgkm)
        if (pref) {
            g2lds16(knext + soff0, &Kt[buf ^ 1][(wave * 2 + 0) * 512]);
            g2lds16(knext + soff1, &Kt[buf ^ 1][(wave * 2 + 1) * 512]);
            g2lds16(vnext + soff0, &Vl[buf ^ 1][(wave * 2 + 0) * 512]);
            g2lds16(vnext + soff1, &Vl[buf ^ 1][(wave * 2 + 1) * 512]);
            knext += 4096;
            vnext += 4096;
        }
        v4f s[4];
#pragma unroll
        for (int nt = 0; nt < 4; nt++) s[nt] = vzero;
        __builtin_amdgcn_s_setprio(1);
#pragma unroll
        for (int nt = 0; nt < 4; nt++) {
            v8bf k0 = *(const v8bf*)(&Kt[buf][nt * 1024 + fb0]);
            v8bf k1 = *(const v8bf*)(&Kt[buf][nt * 1024 + fb1]);
            s[nt] = __builtin_amdgcn_mfma_f32_16x16x32_bf16(k0, qf[0], s[nt], 0, 0, 0);
            s[nt] = __builtin_amdgcn_mfma_f32_16x16x32_bf16(k1, qf[1], s[nt], 0, 0, 0);
        }
        __builtin_amdgcn_s_setprio(0);
        // exp2 + bf16 pack; pa[ntk] = P[keys ntk*16+4kq..+3][q=n16]
        union PW { v4s s4; unsigned u[2]; } pa[4];
#pragma unroll
        for (int ntk = 0; ntk < 4; ntk++) {
            union { v4s s4; __bf16 h[4]; } pk;
#pragma unroll
            for (int r = 0; r < 4; r++) {
                float p = __builtin_amdgcn_exp2f(s[ntk][r]);
                if (diag) {
                    int key = kt * 64 + ntk * 16 + kq * 4 + r;
                    if (key > qglob) p = 0.f;
                }
                pk.h[r] = (__bf16)p;
            }
            pa[ntk].s4 = pk.s4;
        }
        // permlane exchange: build K32 A-frags pf[ks] (lane: P^T[q=n16]
        // [keys ks*32+kq*8..+7]). For word j: 32swap gathers {u01,v01}/{u23,v23},
        // 16swap gathers even/odd rows -> W_j and W_{j+2}.
        union F8 { v8bf v; unsigned u[4]; } pf[2];
#pragma unroll
        for (int ks = 0; ks < 2; ks++) {
#pragma unroll
            for (int j = 0; j < 2; j++) {
                unsigned X = pa[2 * ks].u[j], Y = pa[2 * ks + 1].u[j];
                pl32swap(X, Y);
                pl16swap(X, Y);
                pf[ks].u[j] = X;
                pf[ks].u[j + 2] = Y;
            }
        }
        __builtin_amdgcn_s_setprio(1);
#pragma unroll
        for (int ks = 0; ks < 2; ks++) {
            lacc = __builtin_amdgcn_mfma_f32_16x16x32_bf16(pf[ks].v, vone, lacc, 0, 0, 0);
#pragma unroll
            for (int nt = 0; nt < 4; nt++) {
                v8bf vb = *(const v8bf*)(&Vl[buf][nt * 1024 + (ks ? fb1 : fb0)]);
                o[nt] = __builtin_amdgcn_mfma_f32_16x16x32_bf16(pf[ks].v, vb, o[nt], 0, 0, 0);
            }
        }
        __builtin_amdgcn_s_setprio(0);
    };

    // prologue: stage kt=0 into buf0 (first step's barrier drains vmcnt)
    g2lds16(Kh + soff0, &Kt[0][(wave * 2 + 0) * 512]);
    g2lds16(Kh + soff1, &Kt[0][(wave * 2 + 1) * 512]);
    g2lds16(Vh + soff0, &Vl[0][(wave * 2 + 0) * 512]);
    g2lds16(Vh + soff1, &Vl[0][(wave * 2 + 1) * 512]);
    knext = Kh + 4096;
    vnext = Vh + 4096;

    int kt = 0;
#pragma unroll 1
    while (kt + 2 <= qt) {
        step(IC<0>{}, kt, true, false);
        step(IC<1>{}, kt + 1, true, false);
        kt += 2;
    }
    if (kt < qt) {
        step(IC<0>{}, kt, true, false);
        step(IC<1>{}, kt + 1, false, true);
    } else {
        step(IC<0>{}, kt, false, true);
    }

    float linv[4];
#pragma unroll
    for (int r = 0; r < 4; r++) linv[r] = fastrcp(lacc[r]);
#pragma unroll
    for (int nt = 0; nt < 4; nt++)
#pragma unroll
        for (int r = 0; r < 4; r++) {
            int q = qt * 64 + wave * 16 + kq * 4 + r;
            float val = o[nt][r] * linv[r];
            y[((size_t)b * T_SEQ + q) * D_EMB + h * 64 + nt * 16 + n16] = f2bf(val);
        }
}

// ---------------- launch -----------------------------------------------------
extern "C" void kernel_launch(void* const* d_in, const int* in_sizes, int n_in,
                              void* d_out, int out_size, void* d_ws, size_t ws_size,
                              hipStream_t stream) {
    const float* x = (const float*)d_in[0];
    const float* ln1_g = (const float*)d_in[1];
    const float* ln1_b = (const float*)d_in[2];
    const float* wqkv_w = (const float*)d_in[3];
    const float* wo_w = (const float*)d_in[4];
    const float* wo_b = (const float*)d_in[5];
    const float* ln2_g = (const float*)d_in[6];
    const float* ln2_b = (const float*)d_in[7];
    const float* w1_w = (const float*)d_in[8];
    const float* w1_b = (const float*)d_in[9];
    const float* w2_w = (const float*)d_in[10];
    const float* w2_b = (const float*)d_in[11];
    float* out = (float*)d_out;

    char* ws = (char*)d_ws;
    size_t off = 0;
    auto alloc = [&](size_t bytes) -> void* {
        void* p = ws + off;
        off += (bytes + 255) & ~(size_t)255;
        return p;
    };
    unsigned short* xn = (unsigned short*)alloc((size_t)NTOK * D_EMB * 2);
    unsigned short* wqkvT = (unsigned short*)alloc((size_t)2304 * 768 * 2);
    unsigned short* woT = (unsigned short*)alloc((size_t)768 * 768 * 2);
    unsigned short* w1T = (unsigned short*)alloc((size_t)3072 * 768 * 2);
    unsigned short* w2T = (unsigned short*)alloc((size_t)768 * 3072 * 2);
    unsigned short* Qb = (unsigned short*)alloc((size_t)NTOK * D_EMB * 2);
    unsigned short* Kb = (unsigned short*)alloc((size_t)NTOK * D_EMB * 2);
    unsigned short* Vb = (unsigned short*)alloc((size_t)NTOK * D_EMB * 2);
    unsigned short* yb = (unsigned short*)alloc((size_t)NTOK * D_EMB * 2);
    float* res1 = (float*)alloc((size_t)NTOK * D_EMB * 4);
    unsigned short* Vtb = xn;   // V^T overlay: xn dead during attn
    unsigned short* hbuf = Qb;  // w1 out overlay: spans Qb..yb (all dead then)

    dim3 tb(32, 8);
    tcast_kernel<<<dim3(2304 / 32, 768 / 32), tb, 0, stream>>>(wqkv_w, wqkvT, 768, 2304);
    tcast_kernel<<<dim3(768 / 32, 768 / 32), tb, 0, stream>>>(wo_w, woT, 768, 768);
    tcast_kernel<<<dim3(3072 / 32, 768 / 32), tb, 0, stream>>>(w1_w, w1T, 768, 3072);
    tcast_kernel<<<dim3(768 / 32, 3072 / 32), tb, 0, stream>>>(w2_w, w2T, 3072, 768);

    ln_kernel<<<NTOK, 256, 0, stream>>>(x, ln1_g, ln1_b, xn);

    gemm_kernel<0, 128><<<1152, 256, 0, stream>>>(    // 32KB LDS, 5/CU
        xn, wqkvT, 768, 18, nullptr, nullptr, nullptr, nullptr, Qb, Kb, Vb);

    vtrans_kernel<<<dim3(T_SEQ / 32, 2, 2 * N_HEAD), tb, 0, stream>>>(Vb, Vtb);

    attn_kernel<<<1536, 256, 0, stream>>>(Qb, Kb, Vtb, yb);

    gemm_splitk_kernel<<<384, 512, 0, stream>>>(      // split-K=2, 64KB LDS
        yb, woT, 768, 6, wo_b, x, res1);

    ln_kernel<<<NTOK, 256, 0, stream>>>(res1, ln2_g, ln2_b, xn);

    gemm_kernel<2, 128><<<1536, 256, 0, stream>>>(    // 32KB LDS, 5/CU
        xn, w1T, 768, 24, w1_b, nullptr, nullptr, hbuf, nullptr, nullptr, nullptr);

    gemm_splitk_kernel<<<384, 512, 0, stream>>>(      // split-K=2, 64KB LDS
        hbuf, w2T, 3072, 6, w2_b, res1, out);
}

// Round 10
// 403.982 us; speedup vs baseline: 1.1707x; 1.0210x over previous
//
#include <hip/hip_runtime.h>

#define T_SEQ 4096
#define D_EMB 768
#define N_HEAD 12
#define D_HEAD 64
#define D_MLP 3072
#define NTOK 8192   // B*T
#define QSCALE 0.18033688011112043f  // log2(e)/8, folded into Q at qkv epilogue

typedef __bf16 v8bf __attribute__((ext_vector_type(8)));
typedef float v4f __attribute__((ext_vector_type(4)));
typedef short v4s __attribute__((ext_vector_type(4)));
typedef unsigned v2u __attribute__((ext_vector_type(2)));

template <int N> struct IC { static constexpr int value = N; };

__device__ __forceinline__ unsigned short f2bf(float f) {
    unsigned int u = __float_as_uint(f);
    unsigned int r = (u + 0x7fffu + ((u >> 16) & 1u)) >> 16;
    return (unsigned short)r;
}

__device__ __forceinline__ void g2lds16(const void* g, void* l) {
    __builtin_amdgcn_global_load_lds(
        (const __attribute__((address_space(1))) void*)g,
        (__attribute__((address_space(3))) void*)l, 16, 0, 0);
}

__device__ __forceinline__ float fastrcp(float x) {
#if __has_builtin(__builtin_amdgcn_rcpf)
    return __builtin_amdgcn_rcpf(x);
#else
    return 1.f / x;
#endif
}

// row-swap primitives (gfx950): 32-swap gathers half-pairs, 16-swap gathers
// even/odd 16-rows. Composed they turn the S^T C/D layout into exact K32
// A-fragments -- zero LDS traffic, full-rate VALU.
__device__ __forceinline__ void pl32swap(unsigned& a, unsigned& b) {
#if __has_builtin(__builtin_amdgcn_permlane32_swap)
    v2u r = __builtin_amdgcn_permlane32_swap(a, b, false, false);
    a = r[0]; b = r[1];
#else
    asm volatile("v_permlane32_swap_b32 %0, %1" : "+v"(a), "+v"(b));
#endif
}
__device__ __forceinline__ void pl16swap(unsigned& a, unsigned& b) {
#if __has_builtin(__builtin_amdgcn_permlane16_swap)
    v2u r = __builtin_amdgcn_permlane16_swap(a, b, false, false);
    a = r[0]; b = r[1];
#else
    asm volatile("v_permlane16_swap_b32 %0, %1" : "+v"(a), "+v"(b));
#endif
}

// chunk swizzle for 32-short (4x16B) LDS rows: 16-periodic, makes frag reads
// <=2-way bank-aliased (free) instead of 8-way (2.9x, m136)
__device__ __forceinline__ int sg(int r) { return (r ^ (r >> 2)) & 3; }

// ---------------- weight cast + transpose: fp32 [K][N] -> bf16 [N][K] --------
__global__ void tcast_kernel(const float* __restrict__ in, unsigned short* __restrict__ out,
                             int K, int N) {
    __shared__ float tile[32][33];
    int k0 = blockIdx.y * 32, n0 = blockIdx.x * 32;
    int tx = threadIdx.x, ty = threadIdx.y;
    for (int i = ty; i < 32; i += 8)
        tile[i][tx] = in[(size_t)(k0 + i) * N + n0 + tx];
    __syncthreads();
    for (int i = ty; i < 32; i += 8)
        out[(size_t)(n0 + i) * K + k0 + tx] = f2bf(tile[tx][i]);
}

// ------- V transpose, TILED: [bh][t][64] -> [bh][kt][64d][64k] (8KB tiles) ---
__global__ void vtrans_kernel(const unsigned short* __restrict__ in,
                              unsigned short* __restrict__ out) {
    __shared__ unsigned short tile[32][33];
    size_t base = (size_t)blockIdx.z * T_SEQ * D_HEAD;
    int t0 = blockIdx.x * 32, d0 = blockIdx.y * 32;
    int tx = threadIdx.x, ty = threadIdx.y;
    for (int i = ty; i < 32; i += 8)
        tile[i][tx] = in[base + (size_t)(t0 + i) * D_HEAD + d0 + tx];
    __syncthreads();
    size_t tbase = base + (size_t)(t0 >> 6) * 4096 + (t0 & 32);
    for (int i = ty; i < 32; i += 8)
        out[tbase + (size_t)(d0 + i) * 64 + tx] = tile[tx][i];
}

// ---------------- LayerNorm (768 wide), fp32 in -> bf16 out ------------------
__global__ __launch_bounds__(256) void ln_kernel(const float* __restrict__ x,
                                                 const float* __restrict__ g,
                                                 const float* __restrict__ bta,
                                                 unsigned short* __restrict__ out) {
    int row = blockIdx.x;
    const float* xr = x + (size_t)row * D_EMB;
    int tid = threadIdx.x;
    float v[3];
    float s = 0.f, s2 = 0.f;
#pragma unroll
    for (int i = 0; i < 3; i++) {
        v[i] = xr[tid + i * 256];
        s += v[i];
        s2 += v[i] * v[i];
    }
#pragma unroll
    for (int o = 1; o < 64; o <<= 1) {
        s += __shfl_xor(s, o);
        s2 += __shfl_xor(s2, o);
    }
    __shared__ float red[8];
    int wave = tid >> 6, lane = tid & 63;
    if (lane == 0) { red[wave] = s; red[wave + 4] = s2; }
    __syncthreads();
    s = red[0] + red[1] + red[2] + red[3];
    s2 = red[4] + red[5] + red[6] + red[7];
    float mu = s * (1.f / 768.f);
    float var = s2 * (1.f / 768.f) - mu * mu;
    float rstd = rsqrtf(var + 1e-5f);
#pragma unroll
    for (int i = 0; i < 3; i++) {
        int c = tid + i * 256;
        out[(size_t)row * D_EMB + c] = f2bf((v[i] - mu) * rstd * g[c] + bta[c]);
    }
}

// ---------------- GEMM: C[M,N] = A[M,K] * Bt[N,K]^T, bf16 in, fp32 acc -------
// R6-exact. Swapped-operand MFMA, dbuf global_load_lds staging, XCD-striped
// 1-D grid, sigma-swizzled LDS chunks (compile-time IC<> buffer indices --
// runtime indices break the compiler's immediate-offset folding, R7 lesson).
template <int EPI, int MT>
__global__ __launch_bounds__(256) void gemm_kernel(
    const unsigned short* __restrict__ A, const unsigned short* __restrict__ Bt, int K,
    int Nt, const float* __restrict__ bias, const float* __restrict__ resid,
    float* __restrict__ outF, unsigned short* __restrict__ outB,
    unsigned short* __restrict__ Qb, unsigned short* __restrict__ Kb,
    unsigned short* __restrict__ Vb) {
    constexpr int NAI = (MT == 128) ? 4 : 2;     // act M-subtiles per wave
    __shared__ unsigned short As[2][MT * 32];
    __shared__ unsigned short Bs[2][4096];
    const int tid = threadIdx.x;
    const int wave = tid >> 6, lane = tid & 63;
    const int n16 = lane & 15, kq = lane >> 4;
    const int moff = (wave >> 1) * (MT / 2), noff = (wave & 1) * 64;
    // grid decode: (NTOK/MT)/8 M-tiles per XCD stripe; N inner
    const int id = blockIdx.x;
    const int xcd = id & 7, s = id >> 3;
    const int mt = xcd * (NTOK / MT / 8) + s / Nt, nt_ = s % Nt;
    const long m0 = (long)mt * MT, nb0 = (long)nt_ * 128;

    // staging thread-constants; source chunk sigma-permuted within each 64B row
    const int c0 = (wave * 2 + 0) * 64 + lane;   // B: 512 chunks, 2/thread
    const int c1 = (wave * 2 + 1) * 64 + lane;
    const int r0 = c0 >> 2, r1 = c1 >> 2;
    const unsigned short* bP0 = Bt + (nb0 + r0) * K + (((c0 & 3) ^ sg(r0)) << 3);
    const unsigned short* bP1 = Bt + (nb0 + r1) * K + (((c1 & 3) ^ sg(r1)) << 3);
    const int ca = (MT == 128) ? c0 : (wave * 64 + lane);  // A chunk index
    const int ra = ca >> 2;
    const unsigned short* aP0 = A + (m0 + ra) * K + (((ca & 3) ^ sg(ra)) << 3);
    const unsigned short* aP1 = (MT == 128)
        ? A + (m0 + r1) * K + (((c1 & 3) ^ sg(r1)) << 3) : nullptr;
    // fragment LDS short-indices (loop-invariant; sigma is 16-periodic)
    const int sn = sg(n16);
    const int fw = (noff + n16) * 32 + ((kq ^ sn) << 3);   // weight frags (Bs)
    const int fa = (moff + n16) * 32 + ((kq ^ sn) << 3);   // act frags (As)

    const v4f vzero = {0.f, 0.f, 0.f, 0.f};
    v4f acc[4][NAI];
#pragma unroll
    for (int wi = 0; wi < 4; wi++)
#pragma unroll
        for (int ai = 0; ai < NAI; ai++) acc[wi][ai] = vzero;

    auto stage = [&](auto BUFC, int kpos) {
        constexpr int nb = decltype(BUFC)::value;
        if (MT == 128) {
            g2lds16(aP0 + kpos, &As[nb][(wave * 2 + 0) * 512]);
            g2lds16(aP1 + kpos, &As[nb][(wave * 2 + 1) * 512]);
        } else {
            g2lds16(aP0 + kpos, &As[nb][wave * 512]);  // chunks wave*64..+63
        }
        g2lds16(bP0 + kpos, &Bs[nb][(wave * 2 + 0) * 512]);
        g2lds16(bP1 + kpos, &Bs[nb][(wave * 2 + 1) * 512]);
    };
    auto gstep = [&](auto BUFC, int kpos, bool pref) {
        constexpr int buf = decltype(BUFC)::value;
        __syncthreads();
        if (pref) stage(IC<buf ^ 1>{}, kpos + 32);
        v8bf wf[4], af[NAI];
#pragma unroll
        for (int i = 0; i < 4; i++) wf[i] = *(const v8bf*)(&Bs[buf][fw + i * 512]);
#pragma unroll
        for (int i = 0; i < NAI; i++) af[i] = *(const v8bf*)(&As[buf][fa + i * 512]);
#pragma unroll
        for (int wi = 0; wi < 4; wi++)
#pragma unroll
            for (int ai = 0; ai < NAI; ai++)
                acc[wi][ai] = __builtin_amdgcn_mfma_f32_16x16x32_bf16(wf[wi], af[ai],
                                                                     acc[wi][ai], 0, 0, 0);
    };

    stage(IC<0>{}, 0);
#pragma unroll 1
    for (int k0 = 0; k0 < K; k0 += 64) {
        gstep(IC<0>{}, k0, true);
        gstep(IC<1>{}, k0 + 32, k0 + 64 < K);
    }

#pragma unroll
    for (int wi = 0; wi < 4; wi++) {
#pragma unroll
        for (int ai = 0; ai < NAI; ai++) {
            const long Nb = nb0 + noff + wi * 16 + kq * 4;
            const long M = m0 + moff + ai * 16 + n16;
            if (EPI == 0) {
                int which = (int)(Nb / 768);
                int c = (int)(Nb - which * 768);
                int hh = c >> 6, ii = c & 63;
                int bb = (int)(M >> 12), t = (int)(M & 4095);
                size_t dst = (((size_t)bb * N_HEAD + hh) * T_SEQ + t) * D_HEAD + ii;
                union { uint2 u2; unsigned short us[4]; } pk;
#pragma unroll
                for (int r = 0; r < 4; r++) {
                    float v = acc[wi][ai][r];
                    if (which == 0) v *= QSCALE;
                    pk.us[r] = f2bf(v);
                }
                if (which == 0) *(uint2*)(&Qb[dst]) = pk.u2;
                else if (which == 1) *(uint2*)(&Kb[dst]) = pk.u2;
                else *(uint2*)(&Vb[dst]) = pk.u2;
            } else if (EPI == 1) {
                float4 b4 = *(const float4*)(&bias[Nb]);
                float4 r4 = *(const float4*)(&resid[M * 768 + Nb]);
                float4 o4;
                o4.x = acc[wi][ai][0] + b4.x + r4.x;
                o4.y = acc[wi][ai][1] + b4.y + r4.y;
                o4.z = acc[wi][ai][2] + b4.z + r4.z;
                o4.w = acc[wi][ai][3] + b4.w + r4.w;
                *(float4*)(&outF[M * 768 + Nb]) = o4;
            } else {
                float4 b4 = *(const float4*)(&bias[Nb]);
                union { uint2 u2; unsigned short us[4]; } pk;
#pragma unroll
                for (int r = 0; r < 4; r++) {
                    float t = acc[wi][ai][r] + ((const float*)&b4)[r];
                    // tanh-form GELU via exp2+rcp (~7 VALU vs erff ~40);
                    // max err ~3e-4 << bf16 quantum of the stored output
                    float y = t * (-2.302118131f + t * t * -0.1029433585f);
                    float gl = t * fastrcp(1.f + __builtin_amdgcn_exp2f(y));
                    pk.us[r] = f2bf(gl);
                }
                *(uint2*)(&outB[M * 3072 + Nb]) = pk.u2;
            }
        }
    }
}

// -------- split-K GEMM for thin-N (wo/w2): 512 thr, 2 K-groups, EPI=1 --------
// R8-proven: same tile + grid, waves 0-3 K-half 0 / waves 4-7 K-half 1 (own
// LDS staging, 64KB); steps/block halve, chains/CU double. Group-1 accs pass
// through the dead staging LDS; group-0 adds + bias/resid epilogue.
__global__ __launch_bounds__(512, 4) void gemm_splitk_kernel(
    const unsigned short* __restrict__ A, const unsigned short* __restrict__ Bt, int K,
    int Nt, const float* __restrict__ bias, const float* __restrict__ resid,
    float* __restrict__ outF) {
    __shared__ __align__(16) unsigned short SH[32768];   // 64KB
    const int tid = threadIdx.x;
    const int wave = tid >> 6, lane = tid & 63;
    const int kg = wave >> 2, wv = wave & 3;
    const int n16 = lane & 15, kq = lane >> 4;
    const int moff = (wv >> 1) * 64, noff = (wv & 1) * 64;
    const int id = blockIdx.x;
    const int xcd = id & 7, s = id >> 3;
    const int mt = xcd * (NTOK / 128 / 8) + s / Nt, nt_ = s % Nt;
    const long m0 = (long)mt * 128, nb0 = (long)nt_ * 128;
    const int Kh = K >> 1;

    const int c0 = (wv * 2 + 0) * 64 + lane;
    const int c1 = (wv * 2 + 1) * 64 + lane;
    const int r0 = c0 >> 2, r1 = c1 >> 2;
    const int kb = kg * Kh;
    const unsigned short* bP0 = Bt + (nb0 + r0) * K + ((((c0 & 3) ^ sg(r0)) << 3) + kb);
    const unsigned short* bP1 = Bt + (nb0 + r1) * K + ((((c1 & 3) ^ sg(r1)) << 3) + kb);
    const unsigned short* aP0 = A + (m0 + r0) * K + ((((c0 & 3) ^ sg(r0)) << 3) + kb);
    const unsigned short* aP1 = A + (m0 + r1) * K + ((((c1 & 3) ^ sg(r1)) << 3) + kb);
    const int sn = sg(n16);
    const int fw = (noff + n16) * 32 + ((kq ^ sn) << 3);
    const int fa = (moff + n16) * 32 + ((kq ^ sn) << 3);
    // LDS carve (short idx): A(kg,buf) @ (kg*2+buf)*4096; B(kg,buf) @ 16384+...
    const int abase = kg * 8192, bbase = 16384 + kg * 8192;

    const v4f vzero = {0.f, 0.f, 0.f, 0.f};
    v4f acc[4][4];
#pragma unroll
    for (int wi = 0; wi < 4; wi++)
#pragma unroll
        for (int ai = 0; ai < 4; ai++) acc[wi][ai] = vzero;

    auto stage = [&](auto BUFC, int kpos) {
        constexpr int nb = decltype(BUFC)::value;
        unsigned short* asb = SH + abase + nb * 4096;
        unsigned short* bsb = SH + bbase + nb * 4096;
        g2lds16(aP0 + kpos, asb + (wv * 2 + 0) * 512);
        g2lds16(aP1 + kpos, asb + (wv * 2 + 1) * 512);
        g2lds16(bP0 + kpos, bsb + (wv * 2 + 0) * 512);
        g2lds16(bP1 + kpos, bsb + (wv * 2 + 1) * 512);
    };
    auto gstep = [&](auto BUFC, int kpos, bool pref) {
        constexpr int buf = decltype(BUFC)::value;
        __syncthreads();
        if (pref) stage(IC<buf ^ 1>{}, kpos + 32);
        const unsigned short* asb = SH + abase + buf * 4096;
        const unsigned short* bsb = SH + bbase + buf * 4096;
        v8bf wf[4], af[4];
#pragma unroll
        for (int i = 0; i < 4; i++) wf[i] = *(const v8bf*)(bsb + fw + i * 512);
#pragma unroll
        for (int i = 0; i < 4; i++) af[i] = *(const v8bf*)(asb + fa + i * 512);
#pragma unroll
        for (int wi = 0; wi < 4; wi++)
#pragma unroll
            for (int ai = 0; ai < 4; ai++)
                acc[wi][ai] = __builtin_amdgcn_mfma_f32_16x16x32_bf16(wf[wi], af[ai],
                                                                     acc[wi][ai], 0, 0, 0);
    };

    stage(IC<0>{}, 0);
#pragma unroll 1
    for (int k0 = 0; k0 < Kh; k0 += 64) {
        gstep(IC<0>{}, k0, true);
        gstep(IC<1>{}, k0 + 32, k0 + 64 < Kh);
    }

    // cross-group reduction through the (now dead) staging LDS: 4096 v4f = 64KB
    __syncthreads();                       // all frag reads of SH done
    v4f* ex = (v4f*)SH;
    if (kg == 1) {
#pragma unroll
        for (int wi = 0; wi < 4; wi++)
#pragma unroll
            for (int ai = 0; ai < 4; ai++)
                ex[((wv * 16 + wi * 4 + ai) << 6) + lane] = acc[wi][ai];
    }
    __syncthreads();
    if (kg == 1) return;

#pragma unroll
    for (int wi = 0; wi < 4; wi++) {
#pragma unroll
        for (int ai = 0; ai < 4; ai++) {
            v4f p = ex[((wv * 16 + wi * 4 + ai) << 6) + lane];
            const long Nb = nb0 + noff + wi * 16 + kq * 4;
            const long M = m0 + moff + ai * 16 + n16;
            float4 b4 = *(const float4*)(&bias[Nb]);
            float4 r4 = *(const float4*)(&resid[M * 768 + Nb]);
            float4 o4;
            o4.x = acc[wi][ai][0] + p[0] + b4.x + r4.x;
            o4.y = acc[wi][ai][1] + p[1] + b4.y + r4.y;
            o4.z = acc[wi][ai][2] + p[2] + b4.z + r4.z;
            o4.w = acc[wi][ai][3] + p[3] + b4.w + r4.w;
            *(float4*)(&outF[M * 768 + Nb]) = o4;
        }
    }
}

// ---------------- Flash attention (causal), bf16 Q/K/Vt -> bf16 y ------------
// R9: 512-thread blocks, 8 waves x 16 q = 128 q-rows per block sharing ONE
// K/V staging (K/V frag indices are wave-independent, so staging width is
// free). Halves block-steps (49,920 -> 25,344), barriers, and staging traffic
// for identical MFMA/VALU work; 3 blocks/CU x 8 waves = 24 waves/CU (vs ~11).
// Step count per block = 2*qt2+2 (always even -> clean unroll-2). Causal mask
// auto-generalizes: penultimate step masks waves 0-3's diag, final step
// self-zeroes waves 0-3 entirely (key > qglob uniformly true).
// Per-wave core unchanged: S^T trick, pre-scaled Q, l via ones-MFMA, P in
// registers via permlane32/16_swap -> exact K32 A-frags, setprio on MFMA.
__global__ __launch_bounds__(512) void attn_kernel(const unsigned short* __restrict__ Q,
                                                   const unsigned short* __restrict__ Kg,
                                                   const unsigned short* __restrict__ Vt,
                                                   unsigned short* __restrict__ y) {
    __shared__ unsigned short Kt[2][4096];
    __shared__ unsigned short Vl[2][4096];
    const int tid = threadIdx.x;
    const int wave = tid >> 6, lane = tid & 63;
    const int n16 = lane & 15, kq = lane >> 4;
    const int id = blockIdx.x;
    const int xcd = id & 7, slot = id >> 3;           // slot 0..95
    const int combo = xcd * 3 + (slot % 3);           // 3 bh-combos per XCD
    const int qt2 = 31 - slot / 3;                    // longest blocks first
    const int h = combo % N_HEAD, b = combo / N_HEAD;
    const size_t hoff = (((size_t)b * N_HEAD + h) * T_SEQ) * D_HEAD;
    const unsigned short* Qh = Q + hoff;
    const unsigned short* Kh = Kg + hoff;   // [t][64], k-tile contiguous 8KB
    const unsigned short* Vh = Vt + hoff;   // [kt][64][64] tiled
    const v4f vzero = {0.f, 0.f, 0.f, 0.f};

    // staging: 8 waves x 1 chunk/lane per tile (512 chunks of 16B each)
    const int sC = wave * 64 + lane;
    const int soff = (sC >> 3) * 64 + ((((sC & 7) ^ ((sC >> 3) & 7))) << 3);
    const int fb0 = n16 * 64 + ((kq ^ (n16 & 7)) << 3);
    const int fb1 = n16 * 64 + (((4 + kq) ^ (n16 & 7)) << 3);
    v8bf vone;
#pragma unroll
    for (int j = 0; j < 8; j++) ((unsigned short*)&vone)[j] = 0x3F80;  // bf16 1.0

    const int qglob = qt2 * 128 + wave * 16 + n16;
    v8bf qf[2];
#pragma unroll
    for (int ks = 0; ks < 2; ks++)
        qf[ks] = *(const v8bf*)(&Qh[(size_t)qglob * D_HEAD + ks * 32 + kq * 8]);

    v4f o[4], lacc;
#pragma unroll
    for (int nt = 0; nt < 4; nt++) o[nt] = vzero;
    lacc = vzero;

    const unsigned short* knext;
    const unsigned short* vnext;

    auto step = [&](auto BUFC, int kt, bool pref, bool diag) {
        constexpr int buf = decltype(BUFC)::value;
        __syncthreads();  // buf's tiles ready (vmcnt), prev reads done (lgkm)
        if (pref) {
            g2lds16(knext + soff, &Kt[buf ^ 1][wave * 512]);
            g2lds16(vnext + soff, &Vl[buf ^ 1][wave * 512]);
            knext += 4096;
            vnext += 4096;
        }
        v4f s[4];
#pragma unroll
        for (int nt = 0; nt < 4; nt++) s[nt] = vzero;
        __builtin_amdgcn_s_setprio(1);
#pragma unroll
        for (int nt = 0; nt < 4; nt++) {
            v8bf k0 = *(const v8bf*)(&Kt[buf][nt * 1024 + fb0]);
            v8bf k1 = *(const v8bf*)(&Kt[buf][nt * 1024 + fb1]);
            s[nt] = __builtin_amdgcn_mfma_f32_16x16x32_bf16(k0, qf[0], s[nt], 0, 0, 0);
            s[nt] = __builtin_amdgcn_mfma_f32_16x16x32_bf16(k1, qf[1], s[nt], 0, 0, 0);
        }
        __builtin_amdgcn_s_setprio(0);
        // exp2 + bf16 pack; pa[ntk] = P[keys ntk*16+4kq..+3][q=n16]
        union PW { v4s s4; unsigned u[2]; } pa[4];
#pragma unroll
        for (int ntk = 0; ntk < 4; ntk++) {
            union { v4s s4; __bf16 h[4]; } pk;
#pragma unroll
            for (int r = 0; r < 4; r++) {
                float p = __builtin_amdgcn_exp2f(s[ntk][r]);
                if (diag) {
                    int key = kt * 64 + ntk * 16 + kq * 4 + r;
                    if (key > qglob) p = 0.f;
                }
                pk.h[r] = (__bf16)p;
            }
            pa[ntk].s4 = pk.s4;
        }
        // permlane exchange: build K32 A-frags pf[ks] (lane: P^T[q=n16]
        // [keys ks*32+kq*8..+7]). For word j: 32swap gathers {u01,v01}/{u23,v23},
        // 16swap gathers even/odd rows -> W_j and W_{j+2}.
        union F8 { v8bf v; unsigned u[4]; } pf[2];
#pragma unroll
        for (int ks = 0; ks < 2; ks++) {
#pragma unroll
            for (int j = 0; j < 2; j++) {
                unsigned X = pa[2 * ks].u[j], Y = pa[2 * ks + 1].u[j];
                pl32swap(X, Y);
                pl16swap(X, Y);
                pf[ks].u[j] = X;
                pf[ks].u[j + 2] = Y;
            }
        }
        __builtin_amdgcn_s_setprio(1);
#pragma unroll
        for (int ks = 0; ks < 2; ks++) {
            lacc = __builtin_amdgcn_mfma_f32_16x16x32_bf16(pf[ks].v, vone, lacc, 0, 0, 0);
#pragma unroll
            for (int nt = 0; nt < 4; nt++) {
                v8bf vb = *(const v8bf*)(&Vl[buf][nt * 1024 + (ks ? fb1 : fb0)]);
                o[nt] = __builtin_amdgcn_mfma_f32_16x16x32_bf16(pf[ks].v, vb, o[nt], 0, 0, 0);
            }
        }
        __builtin_amdgcn_s_setprio(0);
    };

    // prologue: stage kt=0 into buf0 (first step's barrier drains vmcnt)
    g2lds16(Kh + soff, &Kt[0][wave * 512]);
    g2lds16(Vh + soff, &Vl[0][wave * 512]);
    knext = Kh + 4096;
    vnext = Vh + 4096;

    const int nst = 2 * qt2 + 2;   // always even
    int kt = 0;
#pragma unroll 1
    while (kt < nst - 2) {
        step(IC<0>{}, kt, true, false);
        step(IC<1>{}, kt + 1, true, false);
        kt += 2;
    }
    step(IC<0>{}, kt, true, true);       // prefetches tile nst-1
    step(IC<1>{}, kt + 1, false, true);  // waves 0-3 fully self-masked here

    float linv[4];
#pragma unroll
    for (int r = 0; r < 4; r++) linv[r] = fastrcp(lacc[r]);
#pragma unroll
    for (int nt = 0; nt < 4; nt++)
#pragma unroll
        for (int r = 0; r < 4; r++) {
            int q = qt2 * 128 + wave * 16 + kq * 4 + r;
            float val = o[nt][r] * linv[r];
            y[((size_t)b * T_SEQ + q) * D_EMB + h * 64 + nt * 16 + n16] = f2bf(val);
        }
}

// ---------------- launch -----------------------------------------------------
extern "C" void kernel_launch(void* const* d_in, const int* in_sizes, int n_in,
                              void* d_out, int out_size, void* d_ws, size_t ws_size,
                              hipStream_t stream) {
    const float* x = (const float*)d_in[0];
    const float* ln1_g = (const float*)d_in[1];
    const float* ln1_b = (const float*)d_in[2];
    const float* wqkv_w = (const float*)d_in[3];
    const float* wo_w = (const float*)d_in[4];
    const float* wo_b = (const float*)d_in[5];
    const float* ln2_g = (const float*)d_in[6];
    const float* ln2_b = (const float*)d_in[7];
    const float* w1_w = (const float*)d_in[8];
    const float* w1_b = (const float*)d_in[9];
    const float* w2_w = (const float*)d_in[10];
    const float* w2_b = (const float*)d_in[11];
    float* out = (float*)d_out;

    char* ws = (char*)d_ws;
    size_t off = 0;
    auto alloc = [&](size_t bytes) -> void* {
        void* p = ws + off;
        off += (bytes + 255) & ~(size_t)255;
        return p;
    };
    unsigned short* xn = (unsigned short*)alloc((size_t)NTOK * D_EMB * 2);
    unsigned short* wqkvT = (unsigned short*)alloc((size_t)2304 * 768 * 2);
    unsigned short* woT = (unsigned short*)alloc((size_t)768 * 768 * 2);
    unsigned short* w1T = (unsigned short*)alloc((size_t)3072 * 768 * 2);
    unsigned short* w2T = (unsigned short*)alloc((size_t)768 * 3072 * 2);
    unsigned short* Qb = (unsigned short*)alloc((size_t)NTOK * D_EMB * 2);
    unsigned short* Kb = (unsigned short*)alloc((size_t)NTOK * D_EMB * 2);
    unsigned short* Vb = (unsigned short*)alloc((size_t)NTOK * D_EMB * 2);
    unsigned short* yb = (unsigned short*)alloc((size_t)NTOK * D_EMB * 2);
    float* res1 = (float*)alloc((size_t)NTOK * D_EMB * 4);
    unsigned short* Vtb = xn;   // V^T overlay: xn dead during attn
    unsigned short* hbuf = Qb;  // w1 out overlay: spans Qb..yb (all dead then)

    dim3 tb(32, 8);
    tcast_kernel<<<dim3(2304 / 32, 768 / 32), tb, 0, stream>>>(wqkv_w, wqkvT, 768, 2304);
    tcast_kernel<<<dim3(768 / 32, 768 / 32), tb, 0, stream>>>(wo_w, woT, 768, 768);
    tcast_kernel<<<dim3(3072 / 32, 768 / 32), tb, 0, stream>>>(w1_w, w1T, 768, 3072);
    tcast_kernel<<<dim3(768 / 32, 3072 / 32), tb, 0, stream>>>(w2_w, w2T, 3072, 768);

    ln_kernel<<<NTOK, 256, 0, stream>>>(x, ln1_g, ln1_b, xn);

    gemm_kernel<0, 128><<<1152, 256, 0, stream>>>(    // 32KB LDS, 5/CU
        xn, wqkvT, 768, 18, nullptr, nullptr, nullptr, nullptr, Qb, Kb, Vb);

    vtrans_kernel<<<dim3(T_SEQ / 32, 2, 2 * N_HEAD), tb, 0, stream>>>(Vb, Vtb);

    attn_kernel<<<768, 512, 0, stream>>>(Qb, Kb, Vtb, yb);

    gemm_splitk_kernel<<<384, 512, 0, stream>>>(      // split-K=2, 64KB LDS
        yb, woT, 768, 6, wo_b, x, res1);

    ln_kernel<<<NTOK, 256, 0, stream>>>(res1, ln2_g, ln2_b, xn);

    gemm_kernel<2, 128><<<1536, 256, 0, stream>>>(    // 32KB LDS, 5/CU
        xn, w1T, 768, 24, w1_b, nullptr, nullptr, hbuf, nullptr, nullptr, nullptr);

    gemm_splitk_kernel<<<384, 512, 0, stream>>>(      // split-K=2, 64KB LDS
        hbuf, w2T, 3072, 6, w2_b, res1, out);
}